// Round 22
// baseline (180.300 us; speedup 1.0000x reference)
//
#include <hip/hip_runtime.h>
#include <cstddef>

#define KSPLIT 16

typedef float vf4 __attribute__((ext_vector_type(4)));
__device__ __forceinline__ float4 ntload4(const float* p) {
    vf4 v = __builtin_nontemporal_load((const vf4*)p);
    return make_float4(v.x, v.y, v.z, v.w);
}

#define DOT4(a, b) ((a).x*(b).x + (a).y*(b).y + (a).z*(b).z + (a).w*(b).w)

// ---------------------------------------------------------------------------
// ws layout (floats):
//   knew 0 (32768) | vnew 32768 (32768) | o_attn 65536 (131072)
//   A 196608 time-shared: qkv_part[16][32][6144] / attn parts / out_part[16][32][4096]
// ---------------------------------------------------------------------------

// ---------------------------------------------------------------------------
// QKV GEMM, outer-product tiled, K-split 16. Grid 768.
// ---------------------------------------------------------------------------
__global__ __launch_bounds__(256) void qkv_tile(
    const float* __restrict__ x,
    const float* __restrict__ wq, const float* __restrict__ wk, const float* __restrict__ wv,
    float* __restrict__ part)
{
    __shared__ float xs[32][68];
    __shared__ float ws[128][68];
    const int t  = threadIdx.x;
    const int ct = blockIdx.x >> 4;
    const int sk = blockIdx.x & 15;
    const int j0 = ct * 128;
    const int kb = sk * 256;

    const float* Wb; int rb;
    if (j0 < 4096)      { Wb = wq; rb = j0; }
    else if (j0 < 5120) { Wb = wk; rb = j0 - 4096; }
    else                { Wb = wv; rb = j0 - 5120; }

    const int b0 = (t >> 5) * 4;
    const int c0 = (t & 31) * 4;

    float4 acc0 = make_float4(0.f,0.f,0.f,0.f);
    float4 acc1 = make_float4(0.f,0.f,0.f,0.f);
    float4 acc2 = make_float4(0.f,0.f,0.f,0.f);
    float4 acc3 = make_float4(0.f,0.f,0.f,0.f);

    for (int sc = 0; sc < 4; ++sc) {
        const int ko = kb + sc * 64;
        __syncthreads();
        #pragma unroll
        for (int i = 0; i < 2; ++i) {
            int idx = t + i * 256;
            int row = idx >> 4, c4 = idx & 15;
            *(float4*)&xs[row][c4 * 4] =
                *(const float4*)&x[(size_t)row * 4096 + ko + c4 * 4];
        }
        #pragma unroll
        for (int i = 0; i < 8; ++i) {
            int idx = t + i * 256;
            int row = idx >> 4, c4 = idx & 15;
            *(float4*)&ws[row][c4 * 4] =
                ntload4(&Wb[(size_t)(rb + row) * 4096 + ko + c4 * 4]);
        }
        __syncthreads();
        #pragma unroll 4
        for (int k = 0; k < 64; k += 4) {
            float4 xv0 = *(const float4*)&xs[b0 + 0][k];
            float4 xv1 = *(const float4*)&xs[b0 + 1][k];
            float4 xv2 = *(const float4*)&xs[b0 + 2][k];
            float4 xv3 = *(const float4*)&xs[b0 + 3][k];
            float4 w0  = *(const float4*)&ws[c0 + 0][k];
            float4 w1  = *(const float4*)&ws[c0 + 1][k];
            float4 w2  = *(const float4*)&ws[c0 + 2][k];
            float4 w3  = *(const float4*)&ws[c0 + 3][k];
            acc0.x += DOT4(xv0,w0); acc0.y += DOT4(xv0,w1); acc0.z += DOT4(xv0,w2); acc0.w += DOT4(xv0,w3);
            acc1.x += DOT4(xv1,w0); acc1.y += DOT4(xv1,w1); acc1.z += DOT4(xv1,w2); acc1.w += DOT4(xv1,w3);
            acc2.x += DOT4(xv2,w0); acc2.y += DOT4(xv2,w1); acc2.z += DOT4(xv2,w2); acc2.w += DOT4(xv2,w3);
            acc3.x += DOT4(xv3,w0); acc3.y += DOT4(xv3,w1); acc3.z += DOT4(xv3,w2); acc3.w += DOT4(xv3,w3);
        }
    }
    float* P = part + (size_t)sk * 196608 + (size_t)b0 * 6144 + j0 + c0;
    *(float4*)&P[0]        = acc0;
    *(float4*)&P[6144]     = acc1;
    *(float4*)&P[2 * 6144] = acc2;
    *(float4*)&P[3 * 6144] = acc3;
}

// ---------------------------------------------------------------------------
__global__ __launch_bounds__(256) void qkv_fix16(
    const float* __restrict__ part,
    const float* __restrict__ cosb, const float* __restrict__ sinb,
    float* __restrict__ q, float* __restrict__ knew, float* __restrict__ vnew)
{
    int idx = blockIdx.x * 256 + threadIdx.x;   // 98304
    if (idx >= 98304) return;
    if (idx < 65536) {
        int b = idx >> 11, r = idx & 2047, h = r >> 6, d = r & 63;
        int c0 = h * 128 + d, c1 = c0 + 64;
        size_t o = (size_t)b * 6144;
        float a0 = 0.f, a1 = 0.f;
        #pragma unroll
        for (int s = 0; s < KSPLIT; ++s) {
            a0 += part[(size_t)s * 196608 + o + c0];
            a1 += part[(size_t)s * 196608 + o + c1];
        }
        float cc1 = cosb[b*128+d],    ss1 = sinb[b*128+d];
        float cc2 = cosb[b*128+d+64], ss2 = sinb[b*128+d+64];
        q[(size_t)b * 4096 + c0] = a0 * cc1 - a1 * ss1;
        q[(size_t)b * 4096 + c1] = a1 * cc2 + a0 * ss2;
    } else if (idx < 81920) {
        int i2 = idx - 65536;
        int b = i2 >> 9, r = i2 & 511, h = r >> 6, d = r & 63;
        int c0 = 4096 + h * 128 + d, c1 = c0 + 64;
        size_t o = (size_t)b * 6144;
        float a0 = 0.f, a1 = 0.f;
        #pragma unroll
        for (int s = 0; s < KSPLIT; ++s) {
            a0 += part[(size_t)s * 196608 + o + c0];
            a1 += part[(size_t)s * 196608 + o + c1];
        }
        float cc1 = cosb[b*128+d],    ss1 = sinb[b*128+d];
        float cc2 = cosb[b*128+d+64], ss2 = sinb[b*128+d+64];
        knew[(size_t)b * 1024 + (c0 - 4096)] = a0 * cc1 - a1 * ss1;
        knew[(size_t)b * 1024 + (c1 - 4096)] = a1 * cc2 + a0 * ss2;
    } else {
        int i3 = idx - 81920;
        int b = i3 >> 9, e = i3 & 511;
        int c0 = 5120 + 2 * e, c1 = c0 + 1;
        size_t o = (size_t)b * 6144;
        float a0 = 0.f, a1 = 0.f;
        #pragma unroll
        for (int s = 0; s < KSPLIT; ++s) {
            a0 += part[(size_t)s * 196608 + o + c0];
            a1 += part[(size_t)s * 196608 + o + c1];
        }
        vnew[(size_t)b * 1024 + (c0 - 5120)] = a0;
        vnew[(size_t)b * 1024 + (c1 - 5120)] = a1;
    }
}

// ---------------------------------------------------------------------------
// Output GEMM, outer-product tiled, K-split 16. Grid 512.
// ---------------------------------------------------------------------------
__global__ __launch_bounds__(256) void out_tile(
    const float* __restrict__ oat, const float* __restrict__ wo,
    float* __restrict__ part)
{
    __shared__ float xs[32][68];
    __shared__ float ws[128][68];
    const int t  = threadIdx.x;
    const int ct = blockIdx.x >> 4;
    const int sk = blockIdx.x & 15;
    const int j0 = ct * 128;
    const int kb = sk * 256;

    const int b0 = (t >> 5) * 4;
    const int c0 = (t & 31) * 4;

    float4 acc0 = make_float4(0.f,0.f,0.f,0.f);
    float4 acc1 = make_float4(0.f,0.f,0.f,0.f);
    float4 acc2 = make_float4(0.f,0.f,0.f,0.f);
    float4 acc3 = make_float4(0.f,0.f,0.f,0.f);

    for (int sc = 0; sc < 4; ++sc) {
        const int ko = kb + sc * 64;
        __syncthreads();
        #pragma unroll
        for (int i = 0; i < 2; ++i) {
            int idx = t + i * 256;
            int row = idx >> 4, c4 = idx & 15;
            *(float4*)&xs[row][c4 * 4] =
                *(const float4*)&oat[(size_t)row * 4096 + ko + c4 * 4];
        }
        #pragma unroll
        for (int i = 0; i < 8; ++i) {
            int idx = t + i * 256;
            int row = idx >> 4, c4 = idx & 15;
            *(float4*)&ws[row][c4 * 4] =
                ntload4(&wo[(size_t)(j0 + row) * 4096 + ko + c4 * 4]);
        }
        __syncthreads();
        #pragma unroll 4
        for (int k = 0; k < 64; k += 4) {
            float4 xv0 = *(const float4*)&xs[b0 + 0][k];
            float4 xv1 = *(const float4*)&xs[b0 + 1][k];
            float4 xv2 = *(const float4*)&xs[b0 + 2][k];
            float4 xv3 = *(const float4*)&xs[b0 + 3][k];
            float4 w0  = *(const float4*)&ws[c0 + 0][k];
            float4 w1  = *(const float4*)&ws[c0 + 1][k];
            float4 w2  = *(const float4*)&ws[c0 + 2][k];
            float4 w3  = *(const float4*)&ws[c0 + 3][k];
            acc0.x += DOT4(xv0,w0); acc0.y += DOT4(xv0,w1); acc0.z += DOT4(xv0,w2); acc0.w += DOT4(xv0,w3);
            acc1.x += DOT4(xv1,w0); acc1.y += DOT4(xv1,w1); acc1.z += DOT4(xv1,w2); acc1.w += DOT4(xv1,w3);
            acc2.x += DOT4(xv2,w0); acc2.y += DOT4(xv2,w1); acc2.z += DOT4(xv2,w2); acc2.w += DOT4(xv2,w3);
            acc3.x += DOT4(xv3,w0); acc3.y += DOT4(xv3,w1); acc3.z += DOT4(xv3,w2); acc3.w += DOT4(xv3,w3);
        }
    }
    float* P = part + (size_t)sk * 131072 + (size_t)b0 * 4096 + j0 + c0;
    *(float4*)&P[0]        = acc0;
    *(float4*)&P[4096]     = acc1;
    *(float4*)&P[2 * 4096] = acc2;
    *(float4*)&P[3 * 4096] = acc3;
}

__global__ __launch_bounds__(256) void out_fix16(
    const float* __restrict__ part, float* __restrict__ out)
{
    int idx = blockIdx.x * 256 + threadIdx.x;   // 131072
    float a = 0.f;
    #pragma unroll
    for (int s = 0; s < KSPLIT; ++s) a += part[(size_t)s * 131072 + idx];
    out[idx] = a;
}

// ---------------------------------------------------------------------------
// Attention: 16-lane groups, no-max exp2 softmax, 2x position unroll,
// non-temporal KV loads. Grid = 256<<spshift, 512 thr.
// ---------------------------------------------------------------------------
__global__ __launch_bounds__(512) void attn_split16(
    const float* __restrict__ q, const float* __restrict__ knew, const float* __restrict__ vnew,
    const float* __restrict__ kcache, const float* __restrict__ vcache,
    const int* __restrict__ block_tables, const int* __restrict__ context_lens,
    const int* __restrict__ slot_mapping,
    int spmask, int spshift,
    float* __restrict__ part_o, float* __restrict__ part_l)
{
    const int blk = blockIdx.x;
    const int sp  = blk & spmask;
    const int bg  = blk >> spshift;
    const int g   = bg & 7;
    const int b   = bg >> 3;
    const int nsplit = spmask + 1;

    const int ctx   = context_lens[b];
    const int chunk = (ctx + nsplit - 1) / nsplit;
    const int p0    = sp * chunk;
    const int p1    = min(ctx, p0 + chunk);

    const int t      = threadIdx.x;
    const int gid    = t >> 4;
    const int lane16 = t & 15;
    const int d0     = lane16 * 8;

    const float SCALE = 0.08838834764831843f * 1.4426950408889634f;
    float4 qa[4], qb[4];
    #pragma unroll
    for (int h = 0; h < 4; ++h) {
        const float* qp = q + (size_t)b * 4096 + (g * 4 + h) * 128 + d0;
        float4 t0 = *(const float4*)qp;
        float4 t1 = *(const float4*)(qp + 4);
        qa[h].x = t0.x * SCALE; qa[h].y = t0.y * SCALE; qa[h].z = t0.z * SCALE; qa[h].w = t0.w * SCALE;
        qb[h].x = t1.x * SCALE; qb[h].y = t1.y * SCALE; qb[h].z = t1.z * SCALE; qb[h].w = t1.w * SCALE;
    }

    float l[4];
    float4 oa[4], ob[4];
    #pragma unroll
    for (int h = 0; h < 4; ++h) {
        l[h] = 0.f;
        oa[h] = make_float4(0.f, 0.f, 0.f, 0.f);
        ob[h] = make_float4(0.f, 0.f, 0.f, 0.f);
    }

    const int slot_new = slot_mapping[b];
    const int* bt = block_tables + b * 128;
    const float* knew_row = knew + ((size_t)b * 8 + g) * 128;
    const float* vnew_row = vnew + ((size_t)b * 8 + g) * 128;

    for (int p = p0 + gid; p < p1; p += 64) {
        const int p2 = p + 32;
        const bool has2 = (p2 < p1);

        int slot1 = bt[p >> 4] * 16 + (p & 15);
        const float *kr1, *vr1;
        if (slot1 == slot_new) { kr1 = knew_row; vr1 = vnew_row; }
        else {
            kr1 = kcache + ((size_t)slot1 * 8 + g) * 128;
            vr1 = vcache + ((size_t)slot1 * 8 + g) * 128;
        }
        float4 ka1  = ntload4(kr1 + d0);
        float4 kb1  = ntload4(kr1 + d0 + 4);
        float4 va1  = ntload4(vr1 + d0);
        float4 vb1  = ntload4(vr1 + d0 + 4);

        float4 ka2, kb2, va2, vb2;
        if (has2) {
            int slot2 = bt[p2 >> 4] * 16 + (p2 & 15);
            const float *kr2, *vr2;
            if (slot2 == slot_new) { kr2 = knew_row; vr2 = vnew_row; }
            else {
                kr2 = kcache + ((size_t)slot2 * 8 + g) * 128;
                vr2 = vcache + ((size_t)slot2 * 8 + g) * 128;
            }
            ka2 = ntload4(kr2 + d0);
            kb2 = ntload4(kr2 + d0 + 4);
            va2 = ntload4(vr2 + d0);
            vb2 = ntload4(vr2 + d0 + 4);
        }

        float s1[4];
        #pragma unroll
        for (int h = 0; h < 4; ++h)
            s1[h] = DOT4(qa[h], ka1) + DOT4(qb[h], kb1);
        #pragma unroll
        for (int mask = 1; mask < 16; mask <<= 1) {
            #pragma unroll
            for (int h = 0; h < 4; ++h)
                s1[h] += __shfl_xor(s1[h], mask);
        }
        #pragma unroll
        for (int h = 0; h < 4; ++h) {
            float w = exp2f(s1[h]);
            l[h] += w;
            oa[h].x += w * va1.x; oa[h].y += w * va1.y; oa[h].z += w * va1.z; oa[h].w += w * va1.w;
            ob[h].x += w * vb1.x; ob[h].y += w * vb1.y; ob[h].z += w * vb1.z; ob[h].w += w * vb1.w;
        }

        if (has2) {
            float s2[4];
            #pragma unroll
            for (int h = 0; h < 4; ++h)
                s2[h] = DOT4(qa[h], ka2) + DOT4(qb[h], kb2);
            #pragma unroll
            for (int mask = 1; mask < 16; mask <<= 1) {
                #pragma unroll
                for (int h = 0; h < 4; ++h)
                    s2[h] += __shfl_xor(s2[h], mask);
            }
            #pragma unroll
            for (int h = 0; h < 4; ++h) {
                float w = exp2f(s2[h]);
                l[h] += w;
                oa[h].x += w * va2.x; oa[h].y += w * va2.y; oa[h].z += w * va2.z; oa[h].w += w * va2.w;
                ob[h].x += w * vb2.x; ob[h].y += w * vb2.y; ob[h].z += w * vb2.z; ob[h].w += w * vb2.w;
            }
        }
    }

    #pragma unroll
    for (int mask = 16; mask < 64; mask <<= 1) {
        #pragma unroll
        for (int h = 0; h < 4; ++h) {
            l[h]   += __shfl_xor(l[h], mask);
            oa[h].x += __shfl_xor(oa[h].x, mask);
            oa[h].y += __shfl_xor(oa[h].y, mask);
            oa[h].z += __shfl_xor(oa[h].z, mask);
            oa[h].w += __shfl_xor(oa[h].w, mask);
            ob[h].x += __shfl_xor(ob[h].x, mask);
            ob[h].y += __shfl_xor(ob[h].y, mask);
            ob[h].z += __shfl_xor(ob[h].z, mask);
            ob[h].w += __shfl_xor(ob[h].w, mask);
        }
    }

    __shared__ __align__(16) float so[8][4][128];
    __shared__ float sl[8][4];
    const int wv   = t >> 6;
    const int lane = t & 63;
    if (lane < 16) {
        #pragma unroll
        for (int h = 0; h < 4; ++h) {
            *(float4*)&so[wv][h][lane * 8]     = oa[h];
            *(float4*)&so[wv][h][lane * 8 + 4] = ob[h];
        }
        if (lane == 0) {
            #pragma unroll
            for (int h = 0; h < 4; ++h) sl[wv][h] = l[h];
        }
    }
    __syncthreads();

    const int h = t >> 7, d = t & 127;
    float O = 0.f;
    #pragma unroll
    for (int w = 0; w < 8; ++w) O += so[w][h][d];
    size_t base = (((size_t)sp * 256 + bg) * 4 + h) * 128 + d;
    part_o[base] = O;
    if (d == 0) {
        float L = 0.f;
        #pragma unroll
        for (int w = 0; w < 8; ++w) L += sl[w][h];
        part_l[((size_t)sp * 256 + bg) * 4 + h] = L;
    }
}

// ---------------------------------------------------------------------------
template <int NS>
__global__ __launch_bounds__(512) void attn_combine_sum(
    const float* __restrict__ part_o, const float* __restrict__ part_l,
    float* __restrict__ o_attn)
{
    const int bg = blockIdx.x;
    const int g = bg & 7, b = bg >> 3;
    const int t = threadIdx.x;
    const int h = t >> 7, d = t & 127;

    float O = 0.f, L = 0.f;
    #pragma unroll
    for (int sp = 0; sp < NS; ++sp) {
        O += part_o[(((size_t)sp * 256 + bg) * 4 + h) * 128 + d];
        L += part_l[((size_t)sp * 256 + bg) * 4 + h];
    }
    o_attn[(size_t)b * 4096 + (g * 4 + h) * 128 + d] = O / L;
}

// ---------------------------------------------------------------------------
// Fallbacks (r18-proven) for small workspaces.
// ---------------------------------------------------------------------------
__device__ __forceinline__ void qkv_map(
    int wid, const float* wq, const float* wk, const float* wv,
    float* q, float* knew, float* vnew,
    const float*& w, float*& dst, int& j0, int& j1, int& rope, int& N, int& d)
{
    if (wid < 2048) { int h = wid >> 6; d = wid & 63;
        w = wq; dst = q;    j0 = h * 128 + d; j1 = j0 + 64; rope = 1; N = 4096; }
    else if (wid < 2560) { int p = wid - 2048; int h = p >> 6; d = p & 63;
        w = wk; dst = knew; j0 = h * 128 + d; j1 = j0 + 64; rope = 1; N = 1024; }
    else { int p = wid - 2560; d = 0;
        w = wv; dst = vnew; j0 = 2 * p;       j1 = 2 * p + 1; rope = 0; N = 1024; }
}

__global__ __launch_bounds__(256) void qkv_rope2(
    const float* __restrict__ x,
    const float* __restrict__ wq, const float* __restrict__ wk, const float* __restrict__ wv,
    const float* __restrict__ cosb, const float* __restrict__ sinb,
    float* __restrict__ q, float* __restrict__ knew, float* __restrict__ vnew)
{
    __shared__ float xs[32][260];
    const int t = threadIdx.x, wvi = t >> 6, lane = t & 63;
    const int widA = blockIdx.x * 8 + wvi * 2, widB = widA + 1;
    const float *wA, *wB; float *dstA, *dstB;
    int jA0, jA1, ropeA, NA, dA, jB0, jB1, ropeB, NB, dB;
    qkv_map(widA, wq, wk, wv, q, knew, vnew, wA, dstA, jA0, jA1, ropeA, NA, dA);
    qkv_map(widB, wq, wk, wv, q, knew, vnew, wB, dstB, jB0, jB1, ropeB, NB, dB);
    const float* A0 = wA + (size_t)jA0 * 4096;
    const float* A1 = wA + (size_t)jA1 * 4096;
    const float* B0 = wB + (size_t)jB0 * 4096;
    const float* B1 = wB + (size_t)jB1 * 4096;
    float acc0[32], acc1[32], acc2[32], acc3[32];
    #pragma unroll
    for (int b = 0; b < 32; ++b) { acc0[b]=0.f; acc1[b]=0.f; acc2[b]=0.f; acc3[b]=0.f; }
    for (int it = 0; it < 16; ++it) {
        __syncthreads();
        #pragma unroll
        for (int i = 0; i < 8; ++i) {
            int idx = t + i * 256, row = idx >> 6, c4 = idx & 63;
            *(float4*)&xs[row][c4 * 4] =
                *(const float4*)&x[(size_t)row * 4096 + it * 256 + c4 * 4];
        }
        __syncthreads();
        const int k = it * 256 + lane * 4;
        float4 wa0 = *(const float4*)&A0[k];
        float4 wa1 = *(const float4*)&A1[k];
        float4 wb0 = *(const float4*)&B0[k];
        float4 wb1 = *(const float4*)&B1[k];
        #pragma unroll
        for (int b = 0; b < 32; ++b) {
            float4 xv = *(const float4*)&xs[b][lane * 4];
            acc0[b] += wa0.x*xv.x + wa0.y*xv.y + wa0.z*xv.z + wa0.w*xv.w;
            acc1[b] += wa1.x*xv.x + wa1.y*xv.y + wa1.z*xv.z + wa1.w*xv.w;
            acc2[b] += wb0.x*xv.x + wb0.y*xv.y + wb0.z*xv.z + wb0.w*xv.w;
            acc3[b] += wb1.x*xv.x + wb1.y*xv.y + wb1.z*xv.z + wb1.w*xv.w;
        }
    }
    #pragma unroll
    for (int mask = 1; mask < 64; mask <<= 1) {
        #pragma unroll
        for (int b = 0; b < 32; ++b) {
            acc0[b] += __shfl_xor(acc0[b], mask);
            acc1[b] += __shfl_xor(acc1[b], mask);
            acc2[b] += __shfl_xor(acc2[b], mask);
            acc3[b] += __shfl_xor(acc3[b], mask);
        }
    }
    if (lane < 32) {
        const int b = lane;
        {   float a0 = acc0[b], a1 = acc1[b];
            if (ropeA) {
                float c1 = cosb[b*128+dA],    s1 = sinb[b*128+dA];
                float c2 = cosb[b*128+dA+64], s2 = sinb[b*128+dA+64];
                dstA[(size_t)b * NA + jA0] = a0 * c1 - a1 * s1;
                dstA[(size_t)b * NA + jA1] = a1 * c2 + a0 * s2;
            } else { dstA[(size_t)b * NA + jA0] = a0; dstA[(size_t)b * NA + jA1] = a1; }
        }
        {   float a0 = acc2[b], a1 = acc3[b];
            if (ropeB) {
                float c1 = cosb[b*128+dB],    s1 = sinb[b*128+dB];
                float c2 = cosb[b*128+dB+64], s2 = sinb[b*128+dB+64];
                dstB[(size_t)b * NB + jB0] = a0 * c1 - a1 * s1;
                dstB[(size_t)b * NB + jB1] = a1 * c2 + a0 * s2;
            } else { dstB[(size_t)b * NB + jB0] = a0; dstB[(size_t)b * NB + jB1] = a1; }
        }
    }
}

__global__ __launch_bounds__(256) void out_gemm2(
    const float* __restrict__ oat, const float* __restrict__ wo, float* __restrict__ out)
{
    __shared__ float xs[32][260];
    const int t = threadIdx.x, wvi = t >> 6, lane = t & 63;
    const int j0 = blockIdx.x * 16 + wvi * 4;
    const float* A0 = wo + (size_t)(j0 + 0) * 4096;
    const float* A1 = wo + (size_t)(j0 + 1) * 4096;
    const float* B0 = wo + (size_t)(j0 + 2) * 4096;
    const float* B1 = wo + (size_t)(j0 + 3) * 4096;
    float acc0[32], acc1[32], acc2[32], acc3[32];
    #pragma unroll
    for (int b = 0; b < 32; ++b) { acc0[b]=0.f; acc1[b]=0.f; acc2[b]=0.f; acc3[b]=0.f; }
    for (int it = 0; it < 16; ++it) {
        __syncthreads();
        #pragma unroll
        for (int i = 0; i < 8; ++i) {
            int idx = t + i * 256, row = idx >> 6, c4 = idx & 63;
            *(float4*)&xs[row][c4 * 4] =
                *(const float4*)&oat[(size_t)row * 4096 + it * 256 + c4 * 4];
        }
        __syncthreads();
        const int k = it * 256 + lane * 4;
        float4 wa0 = *(const float4*)&A0[k];
        float4 wa1 = *(const float4*)&A1[k];
        float4 wb0 = *(const float4*)&B0[k];
        float4 wb1 = *(const float4*)&B1[k];
        #pragma unroll
        for (int b = 0; b < 32; ++b) {
            float4 xv = *(const float4*)&xs[b][lane * 4];
            acc0[b] += wa0.x*xv.x + wa0.y*xv.y + wa0.z*xv.z + wa0.w*xv.w;
            acc1[b] += wa1.x*xv.x + wa1.y*xv.y + wa1.z*xv.z + wa1.w*xv.w;
            acc2[b] += wb0.x*xv.x + wb0.y*xv.y + wb0.z*xv.z + wb0.w*xv.w;
            acc3[b] += wb1.x*xv.x + wb1.y*xv.y + wb1.z*xv.z + wb1.w*xv.w;
        }
    }
    #pragma unroll
    for (int mask = 1; mask < 64; mask <<= 1) {
        #pragma unroll
        for (int b = 0; b < 32; ++b) {
            acc0[b] += __shfl_xor(acc0[b], mask);
            acc1[b] += __shfl_xor(acc1[b], mask);
            acc2[b] += __shfl_xor(acc2[b], mask);
            acc3[b] += __shfl_xor(acc3[b], mask);
        }
    }
    if (lane < 32) {
        const int b = lane;
        out[(size_t)b * 4096 + j0 + 0] = acc0[b];
        out[(size_t)b * 4096 + j0 + 1] = acc1[b];
        out[(size_t)b * 4096 + j0 + 2] = acc2[b];
        out[(size_t)b * 4096 + j0 + 3] = acc3[b];
    }
}

__global__ __launch_bounds__(512) void attn_single(
    const float* __restrict__ q, const float* __restrict__ knew, const float* __restrict__ vnew,
    const float* __restrict__ kcache, const float* __restrict__ vcache,
    const int* __restrict__ block_tables, const int* __restrict__ context_lens,
    const int* __restrict__ slot_mapping,
    float* __restrict__ o_attn)
{
    const int bg = blockIdx.x;
    const int g = bg & 7, b = bg >> 3;
    const int ctx = context_lens[b];
    const int t = threadIdx.x, wv = t >> 6, lane = t & 63, d = lane * 2;
    const float SCALE = 0.08838834764831843f * 1.4426950408889634f;
    float2 qh[4];
    #pragma unroll
    for (int h = 0; h < 4; ++h) {
        float2 qq = *(const float2*)(q + (size_t)b * 4096 + (g * 4 + h) * 128 + d);
        qh[h].x = qq.x * SCALE; qh[h].y = qq.y * SCALE;
    }
    float m[4], l[4], ax[4], ay[4];
    #pragma unroll
    for (int h = 0; h < 4; ++h) { m[h] = -INFINITY; l[h] = 0.f; ax[h] = 0.f; ay[h] = 0.f; }
    const int slot_new = slot_mapping[b];
    const int* bt = block_tables + b * 128;
    const float* knew_row = knew + ((size_t)b * 8 + g) * 128;
    const float* vnew_row = vnew + ((size_t)b * 8 + g) * 128;
    for (int p = wv; p < ctx; p += 8) {
        int slot = bt[p >> 4] * 16 + (p & 15);
        const float* krow;
        const float* vrow;
        if (slot == slot_new) { krow = knew_row; vrow = vnew_row; }
        else {
            krow = kcache + ((size_t)slot * 8 + g) * 128;
            vrow = vcache + ((size_t)slot * 8 + g) * 128;
        }
        float2 kk = *(const float2*)(krow + d);
        float2 vv = *(const float2*)(vrow + d);
        float s[4];
        #pragma unroll
        for (int h = 0; h < 4; ++h)
            s[h] = qh[h].x * kk.x + qh[h].y * kk.y;
        #pragma unroll
        for (int mask = 1; mask < 64; mask <<= 1) {
            #pragma unroll
            for (int h = 0; h < 4; ++h)
                s[h] += __shfl_xor(s[h], mask);
        }
        #pragma unroll
        for (int h = 0; h < 4; ++h) {
            float mn  = fmaxf(m[h], s[h]);
            float c   = exp2f(m[h] - mn);
            float wgt = exp2f(s[h] - mn);
            l[h]  = l[h] * c + wgt;
            ax[h] = ax[h] * c + wgt * vv.x;
            ay[h] = ay[h] * c + wgt * vv.y;
            m[h]  = mn;
        }
    }
    __shared__ float sm[8][4], sl[8][4];
    __shared__ float sacc[8][4][130];
    if (lane == 0) {
        #pragma unroll
        for (int h = 0; h < 4; ++h) { sm[wv][h] = m[h]; sl[wv][h] = l[h]; }
    }
    #pragma unroll
    for (int h = 0; h < 4; ++h) {
        sacc[wv][h][d]     = ax[h];
        sacc[wv][h][d + 1] = ay[h];
    }
    __syncthreads();
    if (wv < 4) {
        const int h = wv;
        float M = -INFINITY;
        #pragma unroll
        for (int w = 0; w < 8; ++w) M = fmaxf(M, sm[w][h]);
        float L = 0.f, ox = 0.f, oy = 0.f;
        #pragma unroll
        for (int w = 0; w < 8; ++w) {
            float mw = sm[w][h];
            float f  = (mw == -INFINITY) ? 0.f : exp2f(mw - M);
            L  += sl[w][h] * f;
            ox += sacc[w][h][d] * f;
            oy += sacc[w][h][d + 1] * f;
        }
        float inv = (L > 0.f) ? 1.f / L : 0.f;
        size_t ob = (size_t)b * 4096 + (g * 4 + h) * 128 + d;
        o_attn[ob]     = ox * inv;
        o_attn[ob + 1] = oy * inv;
    }
}

// ---------------------------------------------------------------------------
extern "C" void kernel_launch(void* const* d_in, const int* in_sizes, int n_in,
                              void* d_out, int out_size, void* d_ws, size_t ws_size,
                              hipStream_t stream)
{
    const float* x       = (const float*)d_in[0];
    const float* wq      = (const float*)d_in[1];
    const float* wk      = (const float*)d_in[2];
    const float* wv      = (const float*)d_in[3];
    const float* wo      = (const float*)d_in[4];
    const float* kcache  = (const float*)d_in[5];
    const float* vcache  = (const float*)d_in[6];
    const float* cosb    = (const float*)d_in[7];
    const float* sinb    = (const float*)d_in[8];
    const int* slot_map  = (const int*)d_in[9];
    const int* ctx_lens  = (const int*)d_in[10];
    const int* btables   = (const int*)d_in[11];

    float* q      = (float*)d_out;       // dead before final out write
    float* wsf    = (float*)d_ws;
    float* knew   = wsf;                 // 32768
    float* vnew   = wsf + 32768;         // 32768
    float* o_attn = wsf + 65536;         // 131072
    float* A      = wsf + 196608;        // time-shared scratch
    float* out    = (float*)d_out;

    const bool tierA = ws_size >= (size_t)(196608 + 3145728) * 4;   // 13.37 MB

    if (tierA) {
        qkv_tile<<<768, 256, 0, stream>>>(x, wq, wk, wv, A);
        qkv_fix16<<<384, 256, 0, stream>>>(A, cosb, sinb, q, knew, vnew);
        float* part_o = A;
        float* part_l = A + 8 * 131072;
        attn_split16<<<2048, 512, 0, stream>>>(
            q, knew, vnew, kcache, vcache, btables, ctx_lens, slot_map,
            7, 3, part_o, part_l);
        attn_combine_sum<8><<<256, 512, 0, stream>>>(part_o, part_l, o_attn);
        out_tile<<<512, 256, 0, stream>>>(o_attn, wo, A);
        out_fix16<<<512, 256, 0, stream>>>(A, out);
    } else {
        qkv_rope2<<<384, 256, 0, stream>>>(x, wq, wk, wv, cosb, sinb, q, knew, vnew);
        attn_single<<<256, 512, 0, stream>>>(
            q, knew, vnew, kcache, vcache, btables, ctx_lens, slot_map, o_attn);
        out_gemm2<<<256, 256, 0, stream>>>(o_attn, wo, out);
    }
}

// Round 23
// 173.800 us; speedup vs baseline: 1.0374x; 1.0374x over previous
//
#include <hip/hip_runtime.h>
#include <cstddef>

#define KSPLIT 16

#define DOT4(a, b) ((a).x*(b).x + (a).y*(b).y + (a).z*(b).z + (a).w*(b).w)

// ---------------------------------------------------------------------------
// ws layout (floats):
//   knew 0 (32768) | vnew 32768 (32768) | o_attn 65536 (131072)
//   A 196608 time-shared: qkv_part[16][32][6144] / attn parts / out_part[16][32][4096]
// ---------------------------------------------------------------------------

// ---------------------------------------------------------------------------
// QKV GEMM, outer-product tiled, K-split 16. Grid 768.
// ---------------------------------------------------------------------------
__global__ __launch_bounds__(256) void qkv_tile(
    const float* __restrict__ x,
    const float* __restrict__ wq, const float* __restrict__ wk, const float* __restrict__ wv,
    float* __restrict__ part)
{
    __shared__ float xs[32][68];
    __shared__ float ws[128][68];
    const int t  = threadIdx.x;
    const int ct = blockIdx.x >> 4;
    const int sk = blockIdx.x & 15;
    const int j0 = ct * 128;
    const int kb = sk * 256;

    const float* Wb; int rb;
    if (j0 < 4096)      { Wb = wq; rb = j0; }
    else if (j0 < 5120) { Wb = wk; rb = j0 - 4096; }
    else                { Wb = wv; rb = j0 - 5120; }

    const int b0 = (t >> 5) * 4;
    const int c0 = (t & 31) * 4;

    float4 acc0 = make_float4(0.f,0.f,0.f,0.f);
    float4 acc1 = make_float4(0.f,0.f,0.f,0.f);
    float4 acc2 = make_float4(0.f,0.f,0.f,0.f);
    float4 acc3 = make_float4(0.f,0.f,0.f,0.f);

    for (int sc = 0; sc < 4; ++sc) {
        const int ko = kb + sc * 64;
        __syncthreads();
        #pragma unroll
        for (int i = 0; i < 2; ++i) {               // xs: 512 float4
            int idx = t + i * 256;
            int row = idx >> 4, c4 = idx & 15;
            *(float4*)&xs[row][c4 * 4] =
                *(const float4*)&x[(size_t)row * 4096 + ko + c4 * 4];
        }
        #pragma unroll
        for (int i = 0; i < 8; ++i) {               // ws: 2048 float4
            int idx = t + i * 256;
            int row = idx >> 4, c4 = idx & 15;
            *(float4*)&ws[row][c4 * 4] =
                *(const float4*)&Wb[(size_t)(rb + row) * 4096 + ko + c4 * 4];
        }
        __syncthreads();
        #pragma unroll 4
        for (int k = 0; k < 64; k += 4) {
            float4 xv0 = *(const float4*)&xs[b0 + 0][k];
            float4 xv1 = *(const float4*)&xs[b0 + 1][k];
            float4 xv2 = *(const float4*)&xs[b0 + 2][k];
            float4 xv3 = *(const float4*)&xs[b0 + 3][k];
            float4 w0  = *(const float4*)&ws[c0 + 0][k];
            float4 w1  = *(const float4*)&ws[c0 + 1][k];
            float4 w2  = *(const float4*)&ws[c0 + 2][k];
            float4 w3  = *(const float4*)&ws[c0 + 3][k];
            acc0.x += DOT4(xv0,w0); acc0.y += DOT4(xv0,w1); acc0.z += DOT4(xv0,w2); acc0.w += DOT4(xv0,w3);
            acc1.x += DOT4(xv1,w0); acc1.y += DOT4(xv1,w1); acc1.z += DOT4(xv1,w2); acc1.w += DOT4(xv1,w3);
            acc2.x += DOT4(xv2,w0); acc2.y += DOT4(xv2,w1); acc2.z += DOT4(xv2,w2); acc2.w += DOT4(xv2,w3);
            acc3.x += DOT4(xv3,w0); acc3.y += DOT4(xv3,w1); acc3.z += DOT4(xv3,w2); acc3.w += DOT4(xv3,w3);
        }
    }
    float* P = part + (size_t)sk * 196608 + (size_t)b0 * 6144 + j0 + c0;
    *(float4*)&P[0]        = acc0;
    *(float4*)&P[6144]     = acc1;
    *(float4*)&P[2 * 6144] = acc2;
    *(float4*)&P[3 * 6144] = acc3;
}

// ---------------------------------------------------------------------------
// Sum 16 K-split partials, apply RoPE, scatter to q/knew/vnew.
// ---------------------------------------------------------------------------
__global__ __launch_bounds__(256) void qkv_fix16(
    const float* __restrict__ part,
    const float* __restrict__ cosb, const float* __restrict__ sinb,
    float* __restrict__ q, float* __restrict__ knew, float* __restrict__ vnew)
{
    int idx = blockIdx.x * 256 + threadIdx.x;   // 98304
    if (idx >= 98304) return;
    if (idx < 65536) {
        int b = idx >> 11, r = idx & 2047, h = r >> 6, d = r & 63;
        int c0 = h * 128 + d, c1 = c0 + 64;
        size_t o = (size_t)b * 6144;
        float a0 = 0.f, a1 = 0.f;
        #pragma unroll
        for (int s = 0; s < KSPLIT; ++s) {
            a0 += part[(size_t)s * 196608 + o + c0];
            a1 += part[(size_t)s * 196608 + o + c1];
        }
        float cc1 = cosb[b*128+d],    ss1 = sinb[b*128+d];
        float cc2 = cosb[b*128+d+64], ss2 = sinb[b*128+d+64];
        q[(size_t)b * 4096 + c0] = a0 * cc1 - a1 * ss1;
        q[(size_t)b * 4096 + c1] = a1 * cc2 + a0 * ss2;
    } else if (idx < 81920) {
        int i2 = idx - 65536;
        int b = i2 >> 9, r = i2 & 511, h = r >> 6, d = r & 63;
        int c0 = 4096 + h * 128 + d, c1 = c0 + 64;
        size_t o = (size_t)b * 6144;
        float a0 = 0.f, a1 = 0.f;
        #pragma unroll
        for (int s = 0; s < KSPLIT; ++s) {
            a0 += part[(size_t)s * 196608 + o + c0];
            a1 += part[(size_t)s * 196608 + o + c1];
        }
        float cc1 = cosb[b*128+d],    ss1 = sinb[b*128+d];
        float cc2 = cosb[b*128+d+64], ss2 = sinb[b*128+d+64];
        knew[(size_t)b * 1024 + (c0 - 4096)] = a0 * cc1 - a1 * ss1;
        knew[(size_t)b * 1024 + (c1 - 4096)] = a1 * cc2 + a0 * ss2;
    } else {
        int i3 = idx - 81920;
        int b = i3 >> 9, e = i3 & 511;
        int c0 = 5120 + 2 * e, c1 = c0 + 1;
        size_t o = (size_t)b * 6144;
        float a0 = 0.f, a1 = 0.f;
        #pragma unroll
        for (int s = 0; s < KSPLIT; ++s) {
            a0 += part[(size_t)s * 196608 + o + c0];
            a1 += part[(size_t)s * 196608 + o + c1];
        }
        vnew[(size_t)b * 1024 + (c0 - 5120)] = a0;
        vnew[(size_t)b * 1024 + (c1 - 5120)] = a1;
    }
}

// ---------------------------------------------------------------------------
// Output GEMM, outer-product tiled, K-split 16. Grid 512.
// ---------------------------------------------------------------------------
__global__ __launch_bounds__(256) void out_tile(
    const float* __restrict__ oat, const float* __restrict__ wo,
    float* __restrict__ part)
{
    __shared__ float xs[32][68];
    __shared__ float ws[128][68];
    const int t  = threadIdx.x;
    const int ct = blockIdx.x >> 4;
    const int sk = blockIdx.x & 15;
    const int j0 = ct * 128;
    const int kb = sk * 256;

    const int b0 = (t >> 5) * 4;
    const int c0 = (t & 31) * 4;

    float4 acc0 = make_float4(0.f,0.f,0.f,0.f);
    float4 acc1 = make_float4(0.f,0.f,0.f,0.f);
    float4 acc2 = make_float4(0.f,0.f,0.f,0.f);
    float4 acc3 = make_float4(0.f,0.f,0.f,0.f);

    for (int sc = 0; sc < 4; ++sc) {
        const int ko = kb + sc * 64;
        __syncthreads();
        #pragma unroll
        for (int i = 0; i < 2; ++i) {
            int idx = t + i * 256;
            int row = idx >> 4, c4 = idx & 15;
            *(float4*)&xs[row][c4 * 4] =
                *(const float4*)&oat[(size_t)row * 4096 + ko + c4 * 4];
        }
        #pragma unroll
        for (int i = 0; i < 8; ++i) {
            int idx = t + i * 256;
            int row = idx >> 4, c4 = idx & 15;
            *(float4*)&ws[row][c4 * 4] =
                *(const float4*)&wo[(size_t)(j0 + row) * 4096 + ko + c4 * 4];
        }
        __syncthreads();
        #pragma unroll 4
        for (int k = 0; k < 64; k += 4) {
            float4 xv0 = *(const float4*)&xs[b0 + 0][k];
            float4 xv1 = *(const float4*)&xs[b0 + 1][k];
            float4 xv2 = *(const float4*)&xs[b0 + 2][k];
            float4 xv3 = *(const float4*)&xs[b0 + 3][k];
            float4 w0  = *(const float4*)&ws[c0 + 0][k];
            float4 w1  = *(const float4*)&ws[c0 + 1][k];
            float4 w2  = *(const float4*)&ws[c0 + 2][k];
            float4 w3  = *(const float4*)&ws[c0 + 3][k];
            acc0.x += DOT4(xv0,w0); acc0.y += DOT4(xv0,w1); acc0.z += DOT4(xv0,w2); acc0.w += DOT4(xv0,w3);
            acc1.x += DOT4(xv1,w0); acc1.y += DOT4(xv1,w1); acc1.z += DOT4(xv1,w2); acc1.w += DOT4(xv1,w3);
            acc2.x += DOT4(xv2,w0); acc2.y += DOT4(xv2,w1); acc2.z += DOT4(xv2,w2); acc2.w += DOT4(xv2,w3);
            acc3.x += DOT4(xv3,w0); acc3.y += DOT4(xv3,w1); acc3.z += DOT4(xv3,w2); acc3.w += DOT4(xv3,w3);
        }
    }
    float* P = part + (size_t)sk * 131072 + (size_t)b0 * 4096 + j0 + c0;
    *(float4*)&P[0]        = acc0;
    *(float4*)&P[4096]     = acc1;
    *(float4*)&P[2 * 4096] = acc2;
    *(float4*)&P[3 * 4096] = acc3;
}

__global__ __launch_bounds__(256) void out_fix16(
    const float* __restrict__ part, float* __restrict__ out)
{
    int idx = blockIdx.x * 256 + threadIdx.x;   // 131072
    float a = 0.f;
    #pragma unroll
    for (int s = 0; s < KSPLIT; ++s) a += part[(size_t)s * 131072 + idx];
    out[idx] = a;
}

// ---------------------------------------------------------------------------
// Attention, 16-lane groups, no-max exp2 softmax (scores bounded: |s*log2e|
// <= ~21 -> exp2 <= 2e6, sums < 1e10, f32-safe). Grid = 256<<spshift, 512 thr.
// ---------------------------------------------------------------------------
__global__ __launch_bounds__(512) void attn_split16(
    const float* __restrict__ q, const float* __restrict__ knew, const float* __restrict__ vnew,
    const float* __restrict__ kcache, const float* __restrict__ vcache,
    const int* __restrict__ block_tables, const int* __restrict__ context_lens,
    const int* __restrict__ slot_mapping,
    int spmask, int spshift,
    float* __restrict__ part_o, float* __restrict__ part_l)
{
    const int blk = blockIdx.x;
    const int sp  = blk & spmask;
    const int bg  = blk >> spshift;
    const int g   = bg & 7;
    const int b   = bg >> 3;
    const int nsplit = spmask + 1;

    const int ctx   = context_lens[b];
    const int chunk = (ctx + nsplit - 1) / nsplit;
    const int p0    = sp * chunk;
    const int p1    = min(ctx, p0 + chunk);

    const int t      = threadIdx.x;
    const int gid    = t >> 4;
    const int lane16 = t & 15;
    const int d0     = lane16 * 8;

    const float SCALE = 0.08838834764831843f * 1.4426950408889634f;
    float4 qa[4], qb[4];
    #pragma unroll
    for (int h = 0; h < 4; ++h) {
        const float* qp = q + (size_t)b * 4096 + (g * 4 + h) * 128 + d0;
        float4 t0 = *(const float4*)qp;
        float4 t1 = *(const float4*)(qp + 4);
        qa[h].x = t0.x * SCALE; qa[h].y = t0.y * SCALE; qa[h].z = t0.z * SCALE; qa[h].w = t0.w * SCALE;
        qb[h].x = t1.x * SCALE; qb[h].y = t1.y * SCALE; qb[h].z = t1.z * SCALE; qb[h].w = t1.w * SCALE;
    }

    float l[4];
    float4 oa[4], ob[4];
    #pragma unroll
    for (int h = 0; h < 4; ++h) {
        l[h] = 0.f;
        oa[h] = make_float4(0.f, 0.f, 0.f, 0.f);
        ob[h] = make_float4(0.f, 0.f, 0.f, 0.f);
    }

    const int slot_new = slot_mapping[b];
    const int* bt = block_tables + b * 128;
    const float* knew_row = knew + ((size_t)b * 8 + g) * 128;
    const float* vnew_row = vnew + ((size_t)b * 8 + g) * 128;

    for (int p = p0 + gid; p < p1; p += 32) {
        int slot = bt[p >> 4] * 16 + (p & 15);
        const float* krow;
        const float* vrow;
        if (slot == slot_new) { krow = knew_row; vrow = vnew_row; }
        else {
            krow = kcache + ((size_t)slot * 8 + g) * 128;
            vrow = vcache + ((size_t)slot * 8 + g) * 128;
        }
        float4 ka  = *(const float4*)(krow + d0);
        float4 kb2 = *(const float4*)(krow + d0 + 4);
        float4 va  = *(const float4*)(vrow + d0);
        float4 vb  = *(const float4*)(vrow + d0 + 4);
        float s[4];
        #pragma unroll
        for (int h = 0; h < 4; ++h) {
            s[h] = qa[h].x*ka.x + qa[h].y*ka.y + qa[h].z*ka.z + qa[h].w*ka.w
                 + qb[h].x*kb2.x + qb[h].y*kb2.y + qb[h].z*kb2.z + qb[h].w*kb2.w;
        }
        #pragma unroll
        for (int mask = 1; mask < 16; mask <<= 1) {
            #pragma unroll
            for (int h = 0; h < 4; ++h)
                s[h] += __shfl_xor(s[h], mask);
        }
        #pragma unroll
        for (int h = 0; h < 4; ++h) {
            float w = exp2f(s[h]);
            l[h] += w;
            oa[h].x += w * va.x; oa[h].y += w * va.y; oa[h].z += w * va.z; oa[h].w += w * va.w;
            ob[h].x += w * vb.x; ob[h].y += w * vb.y; ob[h].z += w * vb.z; ob[h].w += w * vb.w;
        }
    }

    #pragma unroll
    for (int mask = 16; mask < 64; mask <<= 1) {
        #pragma unroll
        for (int h = 0; h < 4; ++h) {
            l[h]   += __shfl_xor(l[h], mask);
            oa[h].x += __shfl_xor(oa[h].x, mask);
            oa[h].y += __shfl_xor(oa[h].y, mask);
            oa[h].z += __shfl_xor(oa[h].z, mask);
            oa[h].w += __shfl_xor(oa[h].w, mask);
            ob[h].x += __shfl_xor(ob[h].x, mask);
            ob[h].y += __shfl_xor(ob[h].y, mask);
            ob[h].z += __shfl_xor(ob[h].z, mask);
            ob[h].w += __shfl_xor(ob[h].w, mask);
        }
    }

    __shared__ __align__(16) float so[8][4][128];
    __shared__ float sl[8][4];
    const int wv   = t >> 6;
    const int lane = t & 63;
    if (lane < 16) {
        #pragma unroll
        for (int h = 0; h < 4; ++h) {
            *(float4*)&so[wv][h][lane * 8]     = oa[h];
            *(float4*)&so[wv][h][lane * 8 + 4] = ob[h];
        }
        if (lane == 0) {
            #pragma unroll
            for (int h = 0; h < 4; ++h) sl[wv][h] = l[h];
        }
    }
    __syncthreads();

    const int h = t >> 7, d = t & 127;
    float O = 0.f;
    #pragma unroll
    for (int w = 0; w < 8; ++w) O += so[w][h][d];
    size_t base = (((size_t)sp * 256 + bg) * 4 + h) * 128 + d;
    part_o[base] = O;
    if (d == 0) {
        float L = 0.f;
        #pragma unroll
        for (int w = 0; w < 8; ++w) L += sl[w][h];
        part_l[((size_t)sp * 256 + bg) * 4 + h] = L;
    }
}

// ---------------------------------------------------------------------------
template <int NS>
__global__ __launch_bounds__(512) void attn_combine_sum(
    const float* __restrict__ part_o, const float* __restrict__ part_l,
    float* __restrict__ o_attn)
{
    const int bg = blockIdx.x;
    const int g = bg & 7, b = bg >> 3;
    const int t = threadIdx.x;
    const int h = t >> 7, d = t & 127;

    float O = 0.f, L = 0.f;
    #pragma unroll
    for (int sp = 0; sp < NS; ++sp) {
        O += part_o[(((size_t)sp * 256 + bg) * 4 + h) * 128 + d];
        L += part_l[((size_t)sp * 256 + bg) * 4 + h];
    }
    o_attn[(size_t)b * 4096 + (g * 4 + h) * 128 + d] = O / L;
}

// ---------------------------------------------------------------------------
// Fallbacks (r18-proven) for small workspaces.
// ---------------------------------------------------------------------------
__device__ __forceinline__ void qkv_map(
    int wid, const float* wq, const float* wk, const float* wv,
    float* q, float* knew, float* vnew,
    const float*& w, float*& dst, int& j0, int& j1, int& rope, int& N, int& d)
{
    if (wid < 2048) { int h = wid >> 6; d = wid & 63;
        w = wq; dst = q;    j0 = h * 128 + d; j1 = j0 + 64; rope = 1; N = 4096; }
    else if (wid < 2560) { int p = wid - 2048; int h = p >> 6; d = p & 63;
        w = wk; dst = knew; j0 = h * 128 + d; j1 = j0 + 64; rope = 1; N = 1024; }
    else { int p = wid - 2560; d = 0;
        w = wv; dst = vnew; j0 = 2 * p;       j1 = 2 * p + 1; rope = 0; N = 1024; }
}

__global__ __launch_bounds__(256) void qkv_rope2(
    const float* __restrict__ x,
    const float* __restrict__ wq, const float* __restrict__ wk, const float* __restrict__ wv,
    const float* __restrict__ cosb, const float* __restrict__ sinb,
    float* __restrict__ q, float* __restrict__ knew, float* __restrict__ vnew)
{
    __shared__ float xs[32][260];
    const int t = threadIdx.x, wvi = t >> 6, lane = t & 63;
    const int widA = blockIdx.x * 8 + wvi * 2, widB = widA + 1;
    const float *wA, *wB; float *dstA, *dstB;
    int jA0, jA1, ropeA, NA, dA, jB0, jB1, ropeB, NB, dB;
    qkv_map(widA, wq, wk, wv, q, knew, vnew, wA, dstA, jA0, jA1, ropeA, NA, dA);
    qkv_map(widB, wq, wk, wv, q, knew, vnew, wB, dstB, jB0, jB1, ropeB, NB, dB);
    const float* A0 = wA + (size_t)jA0 * 4096;
    const float* A1 = wA + (size_t)jA1 * 4096;
    const float* B0 = wB + (size_t)jB0 * 4096;
    const float* B1 = wB + (size_t)jB1 * 4096;
    float acc0[32], acc1[32], acc2[32], acc3[32];
    #pragma unroll
    for (int b = 0; b < 32; ++b) { acc0[b]=0.f; acc1[b]=0.f; acc2[b]=0.f; acc3[b]=0.f; }
    for (int it = 0; it < 16; ++it) {
        __syncthreads();
        #pragma unroll
        for (int i = 0; i < 8; ++i) {
            int idx = t + i * 256, row = idx >> 6, c4 = idx & 63;
            *(float4*)&xs[row][c4 * 4] =
                *(const float4*)&x[(size_t)row * 4096 + it * 256 + c4 * 4];
        }
        __syncthreads();
        const int k = it * 256 + lane * 4;
        float4 wa0 = *(const float4*)&A0[k];
        float4 wa1 = *(const float4*)&A1[k];
        float4 wb0 = *(const float4*)&B0[k];
        float4 wb1 = *(const float4*)&B1[k];
        #pragma unroll
        for (int b = 0; b < 32; ++b) {
            float4 xv = *(const float4*)&xs[b][lane * 4];
            acc0[b] += wa0.x*xv.x + wa0.y*xv.y + wa0.z*xv.z + wa0.w*xv.w;
            acc1[b] += wa1.x*xv.x + wa1.y*xv.y + wa1.z*xv.z + wa1.w*xv.w;
            acc2[b] += wb0.x*xv.x + wb0.y*xv.y + wb0.z*xv.z + wb0.w*xv.w;
            acc3[b] += wb1.x*xv.x + wb1.y*xv.y + wb1.z*xv.z + wb1.w*xv.w;
        }
    }
    #pragma unroll
    for (int mask = 1; mask < 64; mask <<= 1) {
        #pragma unroll
        for (int b = 0; b < 32; ++b) {
            acc0[b] += __shfl_xor(acc0[b], mask);
            acc1[b] += __shfl_xor(acc1[b], mask);
            acc2[b] += __shfl_xor(acc2[b], mask);
            acc3[b] += __shfl_xor(acc3[b], mask);
        }
    }
    if (lane < 32) {
        const int b = lane;
        {   float a0 = acc0[b], a1 = acc1[b];
            if (ropeA) {
                float c1 = cosb[b*128+dA],    s1 = sinb[b*128+dA];
                float c2 = cosb[b*128+dA+64], s2 = sinb[b*128+dA+64];
                dstA[(size_t)b * NA + jA0] = a0 * c1 - a1 * s1;
                dstA[(size_t)b * NA + jA1] = a1 * c2 + a0 * s2;
            } else { dstA[(size_t)b * NA + jA0] = a0; dstA[(size_t)b * NA + jA1] = a1; }
        }
        {   float a0 = acc2[b], a1 = acc3[b];
            if (ropeB) {
                float c1 = cosb[b*128+dB],    s1 = sinb[b*128+dB];
                float c2 = cosb[b*128+dB+64], s2 = sinb[b*128+dB+64];
                dstB[(size_t)b * NB + jB0] = a0 * c1 - a1 * s1;
                dstB[(size_t)b * NB + jB1] = a1 * c2 + a0 * s2;
            } else { dstB[(size_t)b * NB + jB0] = a0; dstB[(size_t)b * NB + jB1] = a1; }
        }
    }
}

__global__ __launch_bounds__(256) void out_gemm2(
    const float* __restrict__ oat, const float* __restrict__ wo, float* __restrict__ out)
{
    __shared__ float xs[32][260];
    const int t = threadIdx.x, wvi = t >> 6, lane = t & 63;
    const int j0 = blockIdx.x * 16 + wvi * 4;
    const float* A0 = wo + (size_t)(j0 + 0) * 4096;
    const float* A1 = wo + (size_t)(j0 + 1) * 4096;
    const float* B0 = wo + (size_t)(j0 + 2) * 4096;
    const float* B1 = wo + (size_t)(j0 + 3) * 4096;
    float acc0[32], acc1[32], acc2[32], acc3[32];
    #pragma unroll
    for (int b = 0; b < 32; ++b) { acc0[b]=0.f; acc1[b]=0.f; acc2[b]=0.f; acc3[b]=0.f; }
    for (int it = 0; it < 16; ++it) {
        __syncthreads();
        #pragma unroll
        for (int i = 0; i < 8; ++i) {
            int idx = t + i * 256, row = idx >> 6, c4 = idx & 63;
            *(float4*)&xs[row][c4 * 4] =
                *(const float4*)&oat[(size_t)row * 4096 + it * 256 + c4 * 4];
        }
        __syncthreads();
        const int k = it * 256 + lane * 4;
        float4 wa0 = *(const float4*)&A0[k];
        float4 wa1 = *(const float4*)&A1[k];
        float4 wb0 = *(const float4*)&B0[k];
        float4 wb1 = *(const float4*)&B1[k];
        #pragma unroll
        for (int b = 0; b < 32; ++b) {
            float4 xv = *(const float4*)&xs[b][lane * 4];
            acc0[b] += wa0.x*xv.x + wa0.y*xv.y + wa0.z*xv.z + wa0.w*xv.w;
            acc1[b] += wa1.x*xv.x + wa1.y*xv.y + wa1.z*xv.z + wa1.w*xv.w;
            acc2[b] += wb0.x*xv.x + wb0.y*xv.y + wb0.z*xv.z + wb0.w*xv.w;
            acc3[b] += wb1.x*xv.x + wb1.y*xv.y + wb1.z*xv.z + wb1.w*xv.w;
        }
    }
    #pragma unroll
    for (int mask = 1; mask < 64; mask <<= 1) {
        #pragma unroll
        for (int b = 0; b < 32; ++b) {
            acc0[b] += __shfl_xor(acc0[b], mask);
            acc1[b] += __shfl_xor(acc1[b], mask);
            acc2[b] += __shfl_xor(acc2[b], mask);
            acc3[b] += __shfl_xor(acc3[b], mask);
        }
    }
    if (lane < 32) {
        const int b = lane;
        out[(size_t)b * 4096 + j0 + 0] = acc0[b];
        out[(size_t)b * 4096 + j0 + 1] = acc1[b];
        out[(size_t)b * 4096 + j0 + 2] = acc2[b];
        out[(size_t)b * 4096 + j0 + 3] = acc3[b];
    }
}

__global__ __launch_bounds__(512) void attn_single(
    const float* __restrict__ q, const float* __restrict__ knew, const float* __restrict__ vnew,
    const float* __restrict__ kcache, const float* __restrict__ vcache,
    const int* __restrict__ block_tables, const int* __restrict__ context_lens,
    const int* __restrict__ slot_mapping,
    float* __restrict__ o_attn)
{
    const int bg = blockIdx.x;
    const int g = bg & 7, b = bg >> 3;
    const int ctx = context_lens[b];
    const int t = threadIdx.x, wv = t >> 6, lane = t & 63, d = lane * 2;
    const float SCALE = 0.08838834764831843f * 1.4426950408889634f;
    float2 qh[4];
    #pragma unroll
    for (int h = 0; h < 4; ++h) {
        float2 qq = *(const float2*)(q + (size_t)b * 4096 + (g * 4 + h) * 128 + d);
        qh[h].x = qq.x * SCALE; qh[h].y = qq.y * SCALE;
    }
    float m[4], l[4], ax[4], ay[4];
    #pragma unroll
    for (int h = 0; h < 4; ++h) { m[h] = -INFINITY; l[h] = 0.f; ax[h] = 0.f; ay[h] = 0.f; }
    const int slot_new = slot_mapping[b];
    const int* bt = block_tables + b * 128;
    const float* knew_row = knew + ((size_t)b * 8 + g) * 128;
    const float* vnew_row = vnew + ((size_t)b * 8 + g) * 128;
    for (int p = wv; p < ctx; p += 8) {
        int slot = bt[p >> 4] * 16 + (p & 15);
        const float* krow;
        const float* vrow;
        if (slot == slot_new) { krow = knew_row; vrow = vnew_row; }
        else {
            krow = kcache + ((size_t)slot * 8 + g) * 128;
            vrow = vcache + ((size_t)slot * 8 + g) * 128;
        }
        float2 kk = *(const float2*)(krow + d);
        float2 vv = *(const float2*)(vrow + d);
        float s[4];
        #pragma unroll
        for (int h = 0; h < 4; ++h)
            s[h] = qh[h].x * kk.x + qh[h].y * kk.y;
        #pragma unroll
        for (int mask = 1; mask < 64; mask <<= 1) {
            #pragma unroll
            for (int h = 0; h < 4; ++h)
                s[h] += __shfl_xor(s[h], mask);
        }
        #pragma unroll
        for (int h = 0; h < 4; ++h) {
            float mn  = fmaxf(m[h], s[h]);
            float c   = exp2f(m[h] - mn);
            float wgt = exp2f(s[h] - mn);
            l[h]  = l[h] * c + wgt;
            ax[h] = ax[h] * c + wgt * vv.x;
            ay[h] = ay[h] * c + wgt * vv.y;
            m[h]  = mn;
        }
    }
    __shared__ float sm[8][4], sl[8][4];
    __shared__ float sacc[8][4][130];
    if (lane == 0) {
        #pragma unroll
        for (int h = 0; h < 4; ++h) { sm[wv][h] = m[h]; sl[wv][h] = l[h]; }
    }
    #pragma unroll
    for (int h = 0; h < 4; ++h) {
        sacc[wv][h][d]     = ax[h];
        sacc[wv][h][d + 1] = ay[h];
    }
    __syncthreads();
    if (wv < 4) {
        const int h = wv;
        float M = -INFINITY;
        #pragma unroll
        for (int w = 0; w < 8; ++w) M = fmaxf(M, sm[w][h]);
        float L = 0.f, ox = 0.f, oy = 0.f;
        #pragma unroll
        for (int w = 0; w < 8; ++w) {
            float mw = sm[w][h];
            float f  = (mw == -INFINITY) ? 0.f : exp2f(mw - M);
            L  += sl[w][h] * f;
            ox += sacc[w][h][d] * f;
            oy += sacc[w][h][d + 1] * f;
        }
        float inv = (L > 0.f) ? 1.f / L : 0.f;
        size_t ob = (size_t)b * 4096 + (g * 4 + h) * 128 + d;
        o_attn[ob]     = ox * inv;
        o_attn[ob + 1] = oy * inv;
    }
}

// ---------------------------------------------------------------------------
extern "C" void kernel_launch(void* const* d_in, const int* in_sizes, int n_in,
                              void* d_out, int out_size, void* d_ws, size_t ws_size,
                              hipStream_t stream)
{
    const float* x       = (const float*)d_in[0];
    const float* wq      = (const float*)d_in[1];
    const float* wk      = (const float*)d_in[2];
    const float* wv      = (const float*)d_in[3];
    const float* wo      = (const float*)d_in[4];
    const float* kcache  = (const float*)d_in[5];
    const float* vcache  = (const float*)d_in[6];
    const float* cosb    = (const float*)d_in[7];
    const float* sinb    = (const float*)d_in[8];
    const int* slot_map  = (const int*)d_in[9];
    const int* ctx_lens  = (const int*)d_in[10];
    const int* btables   = (const int*)d_in[11];

    float* q      = (float*)d_out;       // dead before final out write
    float* wsf    = (float*)d_ws;
    float* knew   = wsf;                 // 32768
    float* vnew   = wsf + 32768;         // 32768
    float* o_attn = wsf + 65536;         // 131072
    float* A      = wsf + 196608;        // time-shared scratch
    float* out    = (float*)d_out;

    const bool tierA = ws_size >= (size_t)(196608 + 3145728) * 4;   // 13.37 MB

    if (tierA) {
        qkv_tile<<<768, 256, 0, stream>>>(x, wq, wk, wv, A);
        qkv_fix16<<<384, 256, 0, stream>>>(A, cosb, sinb, q, knew, vnew);
        float* part_o = A;
        float* part_l = A + 8 * 131072;
        attn_split16<<<2048, 512, 0, stream>>>(
            q, knew, vnew, kcache, vcache, btables, ctx_lens, slot_map,
            7, 3, part_o, part_l);
        attn_combine_sum<8><<<256, 512, 0, stream>>>(part_o, part_l, o_attn);
        out_tile<<<512, 256, 0, stream>>>(o_attn, wo, A);
        out_fix16<<<512, 256, 0, stream>>>(A, out);
    } else {
        qkv_rope2<<<384, 256, 0, stream>>>(x, wq, wk, wv, cosb, sinb, q, knew, vnew);
        attn_single<<<256, 512, 0, stream>>>(
            q, knew, vnew, kcache, vcache, btables, ctx_lens, slot_map, o_attn);
        out_gemm2<<<256, 256, 0, stream>>>(o_attn, wo, out);
    }
}